// Round 13
// baseline (3933.804 us; speedup 1.0000x reference)
//
#include <hip/hip_runtime.h>
#include <math.h>

#define SPAT 196608   // 64*64*48
#define EPSV 1e-5f

// fast gelu: Abramowitz-Stegun 7.1.26 erf approx (abs err <= 1.5e-7)
__device__ __forceinline__ float geluf(float x){
    float ax = fabsf(x)*0.70710678118654752440f;
    float t = __builtin_amdgcn_rcpf(1.0f + 0.3275911f*ax);
    float p = ((((1.061405429f*t - 1.453152027f)*t + 1.421413741f)*t - 0.284496736f)*t + 0.254829592f)*t;
    float e = 1.0f - p*__expf(-ax*ax);
    float er = copysignf(e, x);
    return 0.5f*x*(1.0f + er);
}
__device__ __forceinline__ float wred(float v){
    #pragma unroll
    for(int o=32;o>0;o>>=1) v += __shfl_down(v,o);
    return v;
}

// ---------------- twiddle tables ----------------
__global__ void k_tables(float* tab){
    for(int idx=threadIdx.x; idx<384; idx+=blockDim.x){
        int z = idx>>3, k = idx&7;
        double a = 6.283185307179586476925286766559 * (double)((k*z)%48) / 48.0;
        float c = (float)cos(a), s = (float)sin(a);
        tab[idx]=c; tab[384+idx]=s;
        tab[768 + k*48+z]=c; tab[1152 + k*48+z]=s;
    }
    for(int idx=threadIdx.x; idx<1024; idx+=blockDim.x){
        int y = idx>>4, ki = idx&15;
        int ka = ki<8 ? ki : ki+48;
        double a = 6.283185307179586476925286766559 * (double)((ka*y)%64) / 64.0;
        float c=(float)cos(a), s=(float)sin(a);
        tab[1536+idx]=c; tab[2560+idx]=s;
        tab[3584 + ki*64+y]=c; tab[4608 + ki*64+y]=s;
    }
}

// ---------------- lifting: global-direct, SGPR weights ----------------
__global__ void __launch_bounds__(256) k_lift(const float* __restrict__ x,
                       const float* __restrict__ pw, const float* __restrict__ pb,
                       float* __restrict__ h){
    int t = blockIdx.x*256 + threadIdx.x;      // 393216 total
    int b = (t>=SPAT) ? 1 : 0; int col = t - b*SPAT;
    int xy = col/48, z = col%48;
    const float4* xp = (const float4*)(x + (size_t)t*40);
    float in[40];
    #pragma unroll
    for(int q=0;q<10;q++){
        float4 v = xp[q];
        in[q*4]=v.x; in[q*4+1]=v.y; in[q*4+2]=v.z; in[q*4+3]=v.w;
    }
    float gx = (float)(xy>>6)*(1.0f/63.0f);
    float gy = (float)(xy&63)*(1.0f/63.0f);
    float gz = (float)z*(1.0f/47.0f);
    for(int g=0;g<4;g++){
        const float* w = pw + g*260;
        #pragma unroll 4
        for(int c=0;c<20;c++){
            float a = pb[g*20+c];
            #pragma unroll
            for(int j=0;j<10;j++) a += in[g*10+j]*w[j*20+c];
            a += gx*w[200+c] + gy*w[220+c] + gz*w[240+c];
            h[(size_t)(b*80+g*20+c)*SPAT + col] = a;
        }
    }
}

// ---------------- fused forward z+y DFT + stats partials (+ lazy gelu) ----------------
__global__ void __launch_bounds__(256) k_zy(const float* __restrict__ h,
        float* __restrict__ ybuf, float* __restrict__ partZY,
        const float* __restrict__ tab, int gA,int gB,int gC,int gD, int gflag){
    __shared__ float sp4[4*16*65];              // [q4][k*2+ri][y] stride 65
    __shared__ float cyl[16*65], syl[16*65];    // [ky][y] stride 65
    __shared__ float sred[8];
    int blk = blockIdx.x;
    int x = blk&63; int d=(blk>>6)%20; int r2 = blk/1280; int b = r2&1; int gi = r2>>1;
    int gl4[4]={gA,gB,gC,gD};
    int g = gl4[gi];
    int ch = g*20+d;
    int tid=threadIdx.x;
    int y = tid&63, q4 = tid>>6;   // q4 wave-uniform
    const float4* src = (const float4*)(h + (size_t)(b*80+ch)*SPAT + (size_t)x*3072
                                          + (size_t)(y*48 + q4*12));
    float v[12];
    #pragma unroll
    for(int u=0;u<3;u++){
        float4 t4 = src[u];
        v[u*4]=t4.x; v[u*4+1]=t4.y; v[u*4+2]=t4.z; v[u*4+3]=t4.w;
    }
    if(gflag){
        #pragma unroll
        for(int j=0;j<12;j++) v[j]=geluf(v[j]);
    }
    float s1=0,s2=0;
    #pragma unroll
    for(int j=0;j<12;j++){ s1+=v[j]; s2+=v[j]*v[j]; }
    for(int tt=tid;tt<1024;tt+=256){
        int ki=tt>>6, yy=tt&63;
        cyl[ki*65+yy]=tab[3584+tt]; syl[ki*65+yy]=tab[4608+tt];
    }
    // z partial DFT: twiddles wave-uniform (q4, k, j) -> s_load
    const float* CZ = tab+768  + q4*12;
    const float* SZ = tab+1152 + q4*12;
    #pragma unroll
    for(int k=0;k<8;k++){
        float rr=0, si=0;
        #pragma unroll
        for(int j=0;j<12;j++){ rr += v[j]*CZ[k*48+j]; si += v[j]*SZ[k*48+j]; }
        sp4[(q4*16 + k*2)*65 + y]   = rr;
        sp4[(q4*16 + k*2+1)*65 + y] = -si;
    }
    s1=wred(s1); s2=wred(s2);
    if((tid&63)==0){ sred[(tid>>6)*2]=s1; sred[(tid>>6)*2+1]=s2; }
    __syncthreads();
    if(tid==0){
        size_t pi = ((size_t)(b*80+ch)*64+x)*2;
        partZY[pi]   = sred[0]+sred[2]+sred[4]+sred[6];
        partZY[pi+1] = sred[1]+sred[3]+sred[5]+sred[7];
    }
    // combine 4 partials in place
    #pragma unroll
    for(int j=0;j<4;j++){
        int e = tid + j*256;
        int kri = e>>6, yy = e&63;
        float sum = sp4[kri*65+yy] + sp4[(16+kri)*65+yy]
                  + sp4[(32+kri)*65+yy] + sp4[(48+kri)*65+yy];
        sp4[kri*65+yy] = sum;
    }
    __syncthreads();
    // y-DFT: 128 tasks (ky,kz)
    if(tid<128){
        int ky=tid>>3, kz=tid&7;
        const float* cy = cyl+ky*65; const float* sy = syl+ky*65;
        const float* spr = sp4 + (kz*2)*65;
        const float* spi = sp4 + (kz*2+1)*65;
        float fr=0, fi=0;
        #pragma unroll 8
        for(int yy=0;yy<64;yy++){
            float sr=spr[yy], si=spi[yy];
            float c=cy[yy], s=sy[yy];
            fr += sr*c + si*s;
            fi += si*c - sr*s;
        }
        size_t base = ((size_t)((g*2+b)*20+d)*16 + ky)*1024 + (size_t)(kz*128);
        ybuf[base + x]      = fr;
        ybuf[base + 64 + x] = fi;
    }
}

// ---------------- forward x-DFT + norm1 fold -> per-channel cache ----------------
__global__ void __launch_bounds__(128) k_xdft(const float* __restrict__ ybuf,
        float* __restrict__ fbufC, const float* __restrict__ partZY,
        const float* __restrict__ tab, int gA,int gB,int gC,int gD){
    __shared__ __align__(16) float ylx[16*68];  // [kz*2+ri][x] stride 68
    __shared__ float cxl[16*65], sxl[16*65];
    __shared__ float scs[1];
    int blk = blockIdx.x;
    int kyi = blk&15; int d=(blk>>4)%20; int r2=blk/320; int b=r2&1; int gi=r2>>1;
    int gl4[4]={gA,gB,gC,gD};
    int g=gl4[gi]; int ch=g*20+d;
    int tid=threadIdx.x;
    const float4* src = (const float4*)(ybuf + (((size_t)((g*2+b)*20+d)*16+kyi)*1024));
    #pragma unroll
    for(int u=0;u<2;u++){
        int e=tid+u*128; float4 v=src[e];
        int kzri = e>>4; int xx=(e&15)*4;
        *(float4*)(ylx + kzri*68 + xx) = v;
    }
    for(int tt=tid;tt<1024;tt+=128){
        int ki=tt>>6, y=tt&63;
        cxl[ki*65+y]=tab[3584+tt]; sxl[ki*65+y]=tab[4608+tt];
    }
    float s1=0,s2=0;
    if(tid<64){
        size_t pi=((size_t)(b*80+ch)*64+tid)*2;
        s1=partZY[pi]; s2=partZY[pi+1];
    }
    s1=wred(s1); s2=wred(s2);
    if(tid==0){
        float mean=s1*(1.0f/196608.0f);
        float var=s2*(1.0f/196608.0f)-mean*mean;
        scs[0]=rsqrtf(var+EPSV);
    }
    __syncthreads();
    float sc = scs[0];
    int kxi=tid>>3, kz=tid&7;
    const float* yr = ylx + (kz*2)*68;
    const float* yi = ylx + (kz*2+1)*68;
    const float* cx = cxl + kxi*65;
    const float* sx = sxl + kxi*65;
    float fr=0, fi=0;
    #pragma unroll 8
    for(int xx=0;xx<64;xx++){
        float a=yr[xx], e2=yi[xx];
        float c=cx[xx], s=sx[xx];
        fr += a*c + e2*s;
        fi += e2*c - a*s;
    }
    fr*=sc; fi*=sc;
    if(kxi==0 && kyi==0 && kz==0){ fr=0.0f; fi=0.0f; }
    size_t idx = ((size_t)(b*80+ch)*2048 + (size_t)((kxi*16+kyi)*8+kz))*2;
    fbufC[idx]=fr; fbufC[idx+1]=fi;
}

// ---------------- spectral multiply, PAIR-MERGED (it = blk/320) ----------------
__global__ void __launch_bounds__(256) k_spec2(const float* __restrict__ fbufC,
        const float* __restrict__ sw, float* __restrict__ gbuf,
        float* __restrict__ stat2, int li0,
        int i0, int gA1, int gA2, int i1, int gB1, int gB2){
    __shared__ float part[2112];
    int blk = blockIdx.x;
    int it = blk/320; int r = blk - it*320;
    int m1p = r & 3, o = (r>>2)%20, q = r/80;
    int li = li0 + it;
    int g0 = it ? i1 : i0;
    int g1 = it ? gB1 : gA1;
    int g2 = it ? gB2 : gA2;
    int tid = threadIdx.x;
    int t64 = tid & 63, cc = tid >> 6;
    if(q==0 && m1p==0 && tid<2){
        stat2[((it*2+tid)*20+o)*2]=0.f; stat2[((it*2+tid)*20+o)*2+1]=0.f;
    }
    int offx = (q&1)*8, offy = (q>>1)*8;
    int m1 = m1p*2 + (t64>>5);
    int m2 = (t64>>2)&7;
    int m3 = (t64&3)*2;
    int tw = m1*64 + m2*8 + m3;
    int kxi = m1+offx, kyi = m2+offy;
    int fo = (kxi*16 + kyi)*8 + m3;   // even
    const float4* wp = (const float4*)(sw + (((size_t)(li*4+q)*1600) + o)*1024 + (size_t)tw*2);
    const float4* fb = (const float4*)fbufC + (fo>>1);
    float r00=0,i00=0,r01=0,i01=0, r10=0,i10=0,r11=0,i11=0;
    int c0 = cc*5;
    #pragma unroll
    for(int u=0;u<5;u++){
        int c = c0+u;
        float4 wa = wp[(size_t)c*5120];
        float4 wb4= wp[(size_t)(c+20)*5120];
        float wr0 = wa.x + wb4.x, wi0 = wa.y + wb4.y, wr1 = wa.z + wb4.z, wi1 = wa.w + wb4.w;
        float4 f0 = fb[(size_t)(g0*20+c)*1024];
        float4 f1 = fb[(size_t)(80+g0*20+c)*1024];
        r00 += f0.x*wr0 - f0.y*wi0; i00 += f0.x*wi0 + f0.y*wr0;
        r01 += f0.z*wr1 - f0.w*wi1; i01 += f0.z*wi1 + f0.w*wr1;
        r10 += f1.x*wr0 - f1.y*wi0; i10 += f1.x*wi0 + f1.y*wr0;
        r11 += f1.z*wr1 - f1.w*wi1; i11 += f1.z*wi1 + f1.w*wr1;
    }
    #pragma unroll
    for(int u=0;u<5;u++){
        int c = c0+u;
        float4 wa = wp[(size_t)(c+40)*5120];
        float4 f0 = fb[(size_t)(g1*20+c)*1024];
        float4 f1 = fb[(size_t)(80+g1*20+c)*1024];
        r00 += f0.x*wa.x - f0.y*wa.y; i00 += f0.x*wa.y + f0.y*wa.x;
        r01 += f0.z*wa.z - f0.w*wa.w; i01 += f0.z*wa.w + f0.w*wa.z;
        r10 += f1.x*wa.x - f1.y*wa.y; i10 += f1.x*wa.y + f1.y*wa.x;
        r11 += f1.z*wa.z - f1.w*wa.w; i11 += f1.z*wa.w + f1.w*wa.z;
    }
    #pragma unroll
    for(int u=0;u<5;u++){
        int c = c0+u;
        float4 wa = wp[(size_t)(c+60)*5120];
        float4 f0 = fb[(size_t)(g2*20+c)*1024];
        float4 f1 = fb[(size_t)(80+g2*20+c)*1024];
        r00 += f0.x*wa.x - f0.y*wa.y; i00 += f0.x*wa.y + f0.y*wa.x;
        r01 += f0.z*wa.z - f0.w*wa.w; i01 += f0.z*wa.w + f0.w*wa.z;
        r10 += f1.x*wa.x - f1.y*wa.y; i10 += f1.x*wa.y + f1.y*wa.x;
        r11 += f1.z*wa.z - f1.w*wa.w; i11 += f1.z*wa.w + f1.w*wa.z;
    }
    float vals[8]={r00,i00,r01,i01,r10,i10,r11,i11};
    #pragma unroll
    for(int e=0;e<8;e++) part[t64*33 + e*4 + cc] = vals[e];
    __syncthreads();
    if(cc==0){
        float acc[8];
        #pragma unroll
        for(int e=0;e<8;e++){
            const float* p = part + t64*33 + e*4;
            acc[e] = p[0]+p[1]+p[2]+p[3];
        }
        float* gb = gbuf + (size_t)it*163840;
        float4* gg0 = (float4*)(gb + (size_t)o*4096 + fo*2);
        float4* gg1 = (float4*)(gb + (size_t)(20+o)*4096 + fo*2);
        *gg0 = make_float4(acc[0],acc[1],acc[2],acc[3]);
        *gg1 = make_float4(acc[4],acc[5],acc[6],acc[7]);
    }
}

// ---------------- fused inverse x + y + Parseval stats, PAIR-MERGED ----------------
__global__ void k_inv2(const float* __restrict__ gbuf, float* __restrict__ iybuf,
                       float* __restrict__ stat2, const float* __restrict__ tab){
    __shared__ __align__(16) float gl[4096];
    __shared__ float tmp[256];
    __shared__ float cl[1088], sl[1088];   // [y][ki] stride 17
    __shared__ float ig[4];
    int blk = blockIdx.x;
    int it = blk/2560; int r = blk - it*2560;
    int nx = r&63, o = (r>>6)%20, b = r/1280;
    const float4* src4 = (const float4*)(gbuf + (size_t)it*163840 + (size_t)(b*20+o)*4096);
    for(int t=threadIdx.x;t<1024;t+=blockDim.x) ((float4*)gl)[t]=src4[t];
    for(int t=threadIdx.x;t<1024;t+=blockDim.x){
        int y=t>>4, ki=t&15;
        cl[y*17+ki]=tab[1536+t]; sl[y*17+ki]=tab[2560+t];
    }
    __syncthreads();
    {
        int kyi = threadIdx.x>>3, kz = threadIdx.x&7;
        float ar=0, ai=0;
        #pragma unroll 4
        for(int kxi=0;kxi<16;kxi++){
            float gr = gl[((kxi*16+kyi)*8+kz)*2], gi2 = gl[((kxi*16+kyi)*8+kz)*2+1];
            float c = cl[nx*17+kxi], s = sl[nx*17+kxi];
            ar += gr*c - gi2*s;
            ai += gi2*c + gr*s;
        }
        tmp[threadIdx.x*2]   = ar*(1.0f/64.0f);
        tmp[threadIdx.x*2+1] = ai*(1.0f/64.0f);
    }
    __syncthreads();
    float p1=0,p2=0;
    for(int j=0;j<4;j++){
        int out = threadIdx.x + j*128;
        int ny = out>>3, kz = out&7;
        float ar=0, ai=0;
        #pragma unroll 4
        for(int kyi=0;kyi<16;kyi++){
            float vr = tmp[(kyi*8+kz)*2], vi = tmp[(kyi*8+kz)*2+1];
            float c = cl[ny*17+kyi], s = sl[ny*17+kyi];
            ar += vr*c - vi*s;
            ai += vi*c + vr*s;
        }
        ar *= (1.0f/64.0f); ai *= (1.0f/64.0f);
        size_t idx = ((((size_t)((it*2+b)*20+o)*64+nx)*64+ny)*8+kz)*2;
        iybuf[idx]=ar; iybuf[idx+1]=ai;
        if(kz==0){ p1 += ar; p2 += ar*ar; }
        else p2 += 2.0f*(ar*ar+ai*ai);
    }
    p2 *= (1.0f/48.0f);
    float r1=wred(p1), r2=wred(p2);
    int wv = threadIdx.x>>6;
    if((threadIdx.x&63)==0){ ig[wv*2]=r1; ig[wv*2+1]=r2; }
    __syncthreads();
    if(threadIdx.x==0){
        atomicAdd(&stat2[((it*2+b)*20+o)*2],   ig[0]+ig[2]);
        atomicAdd(&stat2[((it*2+b)*20+o)*2+1], ig[1]+ig[3]);
    }
}

// ---------------- pass D PAIR-MERGED, SEQUENTIAL halves, 384 threads / 1 col each ----------------
__global__ void __launch_bounds__(384) k_passD2(
        const float* __restrict__ iybuf,
        const float* __restrict__ w1, const float* __restrict__ b1,
        const float* __restrict__ w2, const float* __restrict__ b2,
        const float* __restrict__ ww, const float* __restrict__ wb,
        float* __restrict__ h,
        const float* __restrict__ stat2, const float* __restrict__ tab,
        int li0, int i0, int i1, int gA1, int gA2, int gB1, int gB2,
        int fA0,int fA1,int fA2, int fB0,int fB1,int fB2){
    __shared__ __align__(16) float dl[5120];
    __shared__ float m2l[2][20], s2l[2][20];
    __shared__ float czl[384], szl[384];
    int blk = blockIdx.x;
    int nyt = blk&7, nx=(blk>>3)&63, b = blk>>9;
    int tid = threadIdx.x;
    for(int u=tid; u<1280; u+=384){
        int itu = (u>=640)?1:0; int rem = u - itu*640;
        int o = rem>>5, j = rem&31;
        const float4* s4 = (const float4*)(iybuf +
            ((((size_t)((itu*2+b)*20+o)*64+nx)*64 + nyt*8)*16));
        ((float4*)dl)[itu*640 + o*32 + j] = s4[j];
    }
    if(tid<40){
        int itq = tid/20, oq = tid - itq*20;
        float S1 = stat2[((itq*2+b)*20+oq)*2], S2 = stat2[((itq*2+b)*20+oq)*2+1];
        float mean = S1*(1.0f/196608.0f);
        float var = S2*(1.0f/196608.0f) - mean*mean;
        m2l[itq][oq]=mean; s2l[itq][oq]=rsqrtf(var+EPSV);
    }
    if(tid<384){ czl[tid]=tab[768+tid]; szl[tid]=tab[1152+tid]; }
    __syncthreads();
    int p0 = tid;                          // one column per thread
    int nyl = p0/48, nz0 = p0 - nyl*48;
    int sb = (nx*64 + nyt*8)*48;
    const float* hb = h + (size_t)(b*80)*SPAT + sb + p0;
    // ================= iteration A =================
    {
        float vj[20];
        #pragma unroll
        for(int o=0;o<20;o++){
            const float* dd = dl + o*128 + nyl*16;
            float a0 = dd[0];
            #pragma unroll
            for(int k=1;k<8;k++){
                float dr = dd[k*2], di = dd[k*2+1];
                a0 += 2.0f*(dr*czl[k*48+nz0] - di*szl[k*48+nz0]);
            }
            vj[o] = (a0*(1.0f/48.0f) - m2l[0][o])*s2l[0][o];
        }
        const float* W1 = w1 + li0*400; const float* W2 = w2 + li0*400;
        const float* B1 = b1 + li0*20;  const float* B2 = b2 + li0*20;
        float t1[20];
        #pragma unroll
        for(int oo=0;oo<20;oo++){
            float a0=B1[oo];
            #pragma unroll
            for(int j=0;j<20;j++){ a0 += vj[j]*W1[oo*20+j]; }
            t1[oo]=geluf(a0);
        }
        float o0[20];
        #pragma unroll
        for(int oo=0;oo<20;oo++){
            float a0 = B2[oo] + wb[li0*20+oo];
            #pragma unroll
            for(int j=0;j<20;j++){ a0 += t1[j]*W2[oo*20+j]; }
            o0[oo]=a0;
        }
        const float* W = ww + li0*1600;
        for(int c=0;c<20;c++){
            float vv = hb[(size_t)(i0*20+c)*SPAT];
            if(fA0) vv=geluf(vv);
            #pragma unroll
            for(int o=0;o<20;o++) o0[o] += (W[o*80+c] + W[o*80+20+c])*vv;
        }
        for(int c=0;c<20;c++){
            float vv = hb[(size_t)(gA1*20+c)*SPAT];
            if(fA1) vv=geluf(vv);
            #pragma unroll
            for(int o=0;o<20;o++) o0[o] += W[o*80+40+c]*vv;
        }
        for(int c=0;c<20;c++){
            float vv = hb[(size_t)(gA2*20+c)*SPAT];
            if(fA2) vv=geluf(vv);
            #pragma unroll
            for(int o=0;o<20;o++) o0[o] += W[o*80+60+c]*vv;
        }
        #pragma unroll
        for(int o=0;o<20;o++)
            h[(size_t)(b*80+i0*20+o)*SPAT + sb + p0] = o0[o];
    }
    // ================= iteration B ================= (gather set excludes i0)
    {
        int li1 = li0+1;
        float vj[20];
        #pragma unroll
        for(int o=0;o<20;o++){
            const float* dd = dl + 2560 + o*128 + nyl*16;
            float a0 = dd[0];
            #pragma unroll
            for(int k=1;k<8;k++){
                float dr = dd[k*2], di = dd[k*2+1];
                a0 += 2.0f*(dr*czl[k*48+nz0] - di*szl[k*48+nz0]);
            }
            vj[o] = (a0*(1.0f/48.0f) - m2l[1][o])*s2l[1][o];
        }
        const float* W1 = w1 + li1*400; const float* W2 = w2 + li1*400;
        const float* B1 = b1 + li1*20;  const float* B2 = b2 + li1*20;
        float t1[20];
        #pragma unroll
        for(int oo=0;oo<20;oo++){
            float a0=B1[oo];
            #pragma unroll
            for(int j=0;j<20;j++){ a0 += vj[j]*W1[oo*20+j]; }
            t1[oo]=geluf(a0);
        }
        float o0[20];
        #pragma unroll
        for(int oo=0;oo<20;oo++){
            float a0 = B2[oo] + wb[li1*20+oo];
            #pragma unroll
            for(int j=0;j<20;j++){ a0 += t1[j]*W2[oo*20+j]; }
            o0[oo]=a0;
        }
        const float* W = ww + li1*1600;
        for(int c=0;c<20;c++){
            float vv = hb[(size_t)(i1*20+c)*SPAT];
            if(fB0) vv=geluf(vv);
            #pragma unroll
            for(int o=0;o<20;o++) o0[o] += (W[o*80+c] + W[o*80+20+c])*vv;
        }
        for(int c=0;c<20;c++){
            float vv = hb[(size_t)(gB1*20+c)*SPAT];
            if(fB1) vv=geluf(vv);
            #pragma unroll
            for(int o=0;o<20;o++) o0[o] += W[o*80+40+c]*vv;
        }
        for(int c=0;c<20;c++){
            float vv = hb[(size_t)(gB2*20+c)*SPAT];
            if(fB2) vv=geluf(vv);
            #pragma unroll
            for(int o=0;o<20;o++) o0[o] += W[o*80+60+c]*vv;
        }
        #pragma unroll
        for(int o=0;o<20;o++)
            h[(size_t)(b*80+i1*20+o)*SPAT + sb + p0] = o0[o];
    }
}

// ---------------- output head: 2 columns/thread, SGPR weights ----------------
__global__ void __launch_bounds__(256) k_head(const float* __restrict__ h,
        const float* __restrict__ qw1, const float* __restrict__ qb1,
        const float* __restrict__ qw2, const float* __restrict__ qb2,
        float* __restrict__ out){
    int g = blockIdx.x & 3;
    int t = (blockIdx.x>>2)*256 + threadIdx.x;   // 0..196607 column-pairs
    if(t >= 196608) return;
    int b = (t>=98304) ? 1 : 0; int col = (t - b*98304)*2;
    const float* hb = h + (size_t)(b*80+g*20)*SPAT + col;
    float2 in20[20];
    #pragma unroll
    for(int j=0;j<20;j++) in20[j] = *(const float2*)(hb + (size_t)j*SPAT);
    float2 o20[20];
    #pragma unroll
    for(int o2=0;o2<20;o2++){ float bv = qb2[g*20+o2]; o20[o2].x=bv; o20[o2].y=bv; }
    for(int o8=0;o8<80;o8++){
        float bv = qb1[g*80+o8];
        float a0 = bv, a1 = bv;
        #pragma unroll
        for(int j=0;j<20;j++){
            float w = qw1[g*1600 + o8*20 + j];
            a0 += in20[j].x*w; a1 += in20[j].y*w;
        }
        a0 = geluf(a0); a1 = geluf(a1);
        #pragma unroll
        for(int o2=0;o2<20;o2++){
            float w = qw2[g*1600 + o2*80 + o8];
            o20[o2].x += a0*w; o20[o2].y += a1*w;
        }
    }
    float* op0 = out + ((size_t)(b*SPAT)+col)*80 + g*20;
    float* op1 = op0 + 80;
    #pragma unroll
    for(int q2=0;q2<5;q2++){
        *(float4*)(op0 + q2*4) = make_float4(o20[q2*4].x,o20[q2*4+1].x,o20[q2*4+2].x,o20[q2*4+3].x);
        *(float4*)(op1 + q2*4) = make_float4(o20[q2*4].y,o20[q2*4+1].y,o20[q2*4+2].y,o20[q2*4+3].y);
    }
}

extern "C" void kernel_launch(void* const* d_in, const int* in_sizes, int n_in,
                              void* d_out, int out_size, void* d_ws, size_t ws_size,
                              hipStream_t stream){
    (void)in_sizes; (void)n_in; (void)out_size;
    const float* x    = (const float*)d_in[0];
    const float* p_w  = (const float*)d_in[1];
    const float* p_b  = (const float*)d_in[2];
    const float* spec = (const float*)d_in[3];
    const float* w1   = (const float*)d_in[4];
    const float* b1   = (const float*)d_in[5];
    const float* w2   = (const float*)d_in[6];
    const float* b2   = (const float*)d_in[7];
    const float* ww   = (const float*)d_in[8];
    const float* wb   = (const float*)d_in[9];
    const float* qw1  = (const float*)d_in[10];
    const float* qb1  = (const float*)d_in[11];
    const float* qw2  = (const float*)d_in[12];
    const float* qb2  = (const float*)d_in[13];
    float* out = (float*)d_out;
    float* ws  = (float*)d_ws;

    if(ws_size < (size_t)40330912*4) return;  // ~161 MB scratch

    float* h      = ws;                       // 31,457,280
    float* ybuf   = ws + 31457280;            //  2,621,440
    float* gbuf   = ws + 34078720;            //    327,680 (2 iters)
    float* iyb    = ws + 34406400;            //  5,242,880 (2 iters)
    float* fbufC  = ws + 39649280;            //    655,360
    float* partZY = ws + 40304640;            //     20,480
    float* stat2  = ws + 40325120;            //        160 (2 iters)
    float* tab    = ws + 40325280;            //      5,632

    k_tables<<<1,256,0,stream>>>(tab);
    k_lift<<<1536,256,0,stream>>>(x, p_w, p_b, h);

    static const int ORD3[4][3] = {{0,1,2},{1,2,3},{2,3,0},{3,0,1}};
    for(int l=0;l<4;l++){
        int lf = (l>0)?1:0;
        for(int bi=0;bi<2;bi++){
            if(bi==0){
                // all 4 groups from pre-layer h (iters 0,1 read only pre-layer channels)
                k_zy  <<<10240,256,0,stream>>>(h, ybuf, partZY, tab, 0,1,2,3, lf);
                k_xdft<<< 2560,128,0,stream>>>(ybuf, fbufC, partZY, tab, 0,1,2,3);
            } else {
                // groups 0,1 freshly updated this layer -> no gelu
                k_zy  <<< 5120,256,0,stream>>>(h, ybuf, partZY, tab, 0,1,0,0, 0);
                k_xdft<<< 1280,128,0,stream>>>(ybuf, fbufC, partZY, tab, 0,1,0,0);
            }
            int i0 = bi*2, i1 = i0+1, li0 = l*4+i0;
            int gA1=ORD3[i0][1], gA2=ORD3[i0][2];
            int gB1=ORD3[i1][1], gB2=ORD3[i1][2];
            k_spec2<<< 640,256,0,stream>>>(fbufC, spec, gbuf, stat2, li0,
                                           i0,gA1,gA2, i1,gB1,gB2);
            k_inv2 <<<5120,128,0,stream>>>(gbuf, iyb, stat2, tab);
            int fA0 = lf;
            int fA1 = (gA1<i0)?0:lf;
            int fA2 = (gA2<i0)?0:lf;
            int fB0 = lf;
            int fB1 = (gB1<i1)?0:lf;
            int fB2 = (gB2<i1)?0:lf;
            k_passD2<<<1024,384,0,stream>>>(iyb, w1,b1,w2,b2, ww,wb, h, stat2, tab,
                                            li0, i0,i1, gA1,gA2, gB1,gB2,
                                            fA0,fA1,fA2, fB0,fB1,fB2);
        }
    }
    k_head<<<3072,256,0,stream>>>(h, qw1, qb1, qw2, qb2, out);
}

// Round 14
// 3008.411 us; speedup vs baseline: 1.3076x; 1.3076x over previous
//
#include <hip/hip_runtime.h>
#include <math.h>

#define SPAT 196608   // 64*64*48
#define EPSV 1e-5f

// fast gelu: Abramowitz-Stegun 7.1.26 erf approx (abs err <= 1.5e-7)
__device__ __forceinline__ float geluf(float x){
    float ax = fabsf(x)*0.70710678118654752440f;
    float t = __builtin_amdgcn_rcpf(1.0f + 0.3275911f*ax);
    float p = ((((1.061405429f*t - 1.453152027f)*t + 1.421413741f)*t - 0.284496736f)*t + 0.254829592f)*t;
    float e = 1.0f - p*__expf(-ax*ax);
    float er = copysignf(e, x);
    return 0.5f*x*(1.0f + er);
}
__device__ __forceinline__ float wred(float v){
    #pragma unroll
    for(int o=32;o>0;o>>=1) v += __shfl_down(v,o);
    return v;
}

// ---------------- twiddle tables ----------------
__global__ void k_tables(float* tab){
    for(int idx=threadIdx.x; idx<384; idx+=blockDim.x){
        int z = idx>>3, k = idx&7;
        double a = 6.283185307179586476925286766559 * (double)((k*z)%48) / 48.0;
        float c = (float)cos(a), s = (float)sin(a);
        tab[idx]=c; tab[384+idx]=s;
        tab[768 + k*48+z]=c; tab[1152 + k*48+z]=s;
    }
    for(int idx=threadIdx.x; idx<1024; idx+=blockDim.x){
        int y = idx>>4, ki = idx&15;
        int ka = ki<8 ? ki : ki+48;
        double a = 6.283185307179586476925286766559 * (double)((ka*y)%64) / 64.0;
        float c=(float)cos(a), s=(float)sin(a);
        tab[1536+idx]=c; tab[2560+idx]=s;
        tab[3584 + ki*64+y]=c; tab[4608 + ki*64+y]=s;
    }
}

// ---------------- lifting: global-direct, SGPR weights ----------------
__global__ void __launch_bounds__(256) k_lift(const float* __restrict__ x,
                       const float* __restrict__ pw, const float* __restrict__ pb,
                       float* __restrict__ h){
    int t = blockIdx.x*256 + threadIdx.x;      // 393216 total
    int b = (t>=SPAT) ? 1 : 0; int col = t - b*SPAT;
    int xy = col/48, z = col%48;
    const float4* xp = (const float4*)(x + (size_t)t*40);
    float in[40];
    #pragma unroll
    for(int q=0;q<10;q++){
        float4 v = xp[q];
        in[q*4]=v.x; in[q*4+1]=v.y; in[q*4+2]=v.z; in[q*4+3]=v.w;
    }
    float gx = (float)(xy>>6)*(1.0f/63.0f);
    float gy = (float)(xy&63)*(1.0f/63.0f);
    float gz = (float)z*(1.0f/47.0f);
    for(int g=0;g<4;g++){
        const float* w = pw + g*260;
        #pragma unroll 4
        for(int c=0;c<20;c++){
            float a = pb[g*20+c];
            #pragma unroll
            for(int j=0;j<10;j++) a += in[g*10+j]*w[j*20+c];
            a += gx*w[200+c] + gy*w[220+c] + gz*w[240+c];
            h[(size_t)(b*80+g*20+c)*SPAT + col] = a;
        }
    }
}

// ---------------- fused forward z+y DFT + stats partials (+ lazy gelu) ----------------
__global__ void __launch_bounds__(256) k_zy(const float* __restrict__ h,
        float* __restrict__ ybuf, float* __restrict__ partZY,
        const float* __restrict__ tab, int gA,int gB,int gC,int gD, int gflag){
    __shared__ float sp4[4*16*65];              // [q4][k*2+ri][y] stride 65
    __shared__ float cyl[16*65], syl[16*65];    // [ky][y] stride 65
    __shared__ float sred[8];
    int blk = blockIdx.x;
    int x = blk&63; int d=(blk>>6)%20; int r2 = blk/1280; int b = r2&1; int gi = r2>>1;
    int gl4[4]={gA,gB,gC,gD};
    int g = gl4[gi];
    int ch = g*20+d;
    int tid=threadIdx.x;
    int y = tid&63, q4 = tid>>6;   // q4 wave-uniform
    const float4* src = (const float4*)(h + (size_t)(b*80+ch)*SPAT + (size_t)x*3072
                                          + (size_t)(y*48 + q4*12));
    float v[12];
    #pragma unroll
    for(int u=0;u<3;u++){
        float4 t4 = src[u];
        v[u*4]=t4.x; v[u*4+1]=t4.y; v[u*4+2]=t4.z; v[u*4+3]=t4.w;
    }
    if(gflag){
        #pragma unroll
        for(int j=0;j<12;j++) v[j]=geluf(v[j]);
    }
    float s1=0,s2=0;
    #pragma unroll
    for(int j=0;j<12;j++){ s1+=v[j]; s2+=v[j]*v[j]; }
    for(int tt=tid;tt<1024;tt+=256){
        int ki=tt>>6, yy=tt&63;
        cyl[ki*65+yy]=tab[3584+tt]; syl[ki*65+yy]=tab[4608+tt];
    }
    // z partial DFT: twiddles wave-uniform (q4, k, j) -> s_load
    const float* CZ = tab+768  + q4*12;
    const float* SZ = tab+1152 + q4*12;
    #pragma unroll
    for(int k=0;k<8;k++){
        float rr=0, si=0;
        #pragma unroll
        for(int j=0;j<12;j++){ rr += v[j]*CZ[k*48+j]; si += v[j]*SZ[k*48+j]; }
        sp4[(q4*16 + k*2)*65 + y]   = rr;
        sp4[(q4*16 + k*2+1)*65 + y] = -si;
    }
    s1=wred(s1); s2=wred(s2);
    if((tid&63)==0){ sred[(tid>>6)*2]=s1; sred[(tid>>6)*2+1]=s2; }
    __syncthreads();
    if(tid==0){
        size_t pi = ((size_t)(b*80+ch)*64+x)*2;
        partZY[pi]   = sred[0]+sred[2]+sred[4]+sred[6];
        partZY[pi+1] = sred[1]+sred[3]+sred[5]+sred[7];
    }
    // combine 4 partials in place
    #pragma unroll
    for(int j=0;j<4;j++){
        int e = tid + j*256;
        int kri = e>>6, yy = e&63;
        float sum = sp4[kri*65+yy] + sp4[(16+kri)*65+yy]
                  + sp4[(32+kri)*65+yy] + sp4[(48+kri)*65+yy];
        sp4[kri*65+yy] = sum;
    }
    __syncthreads();
    // y-DFT: 128 tasks (ky,kz)
    if(tid<128){
        int ky=tid>>3, kz=tid&7;
        const float* cy = cyl+ky*65; const float* sy = syl+ky*65;
        const float* spr = sp4 + (kz*2)*65;
        const float* spi = sp4 + (kz*2+1)*65;
        float fr=0, fi=0;
        #pragma unroll 8
        for(int yy=0;yy<64;yy++){
            float sr=spr[yy], si=spi[yy];
            float c=cy[yy], s=sy[yy];
            fr += sr*c + si*s;
            fi += si*c - sr*s;
        }
        size_t base = ((size_t)((g*2+b)*20+d)*16 + ky)*1024 + (size_t)(kz*128);
        ybuf[base + x]      = fr;
        ybuf[base + 64 + x] = fi;
    }
}

// ---------------- forward x-DFT + norm1 fold -> per-channel cache ----------------
__global__ void __launch_bounds__(128) k_xdft(const float* __restrict__ ybuf,
        float* __restrict__ fbufC, const float* __restrict__ partZY,
        const float* __restrict__ tab, int gA,int gB,int gC,int gD){
    __shared__ __align__(16) float ylx[16*68];  // [kz*2+ri][x] stride 68
    __shared__ float cxl[16*65], sxl[16*65];
    __shared__ float scs[1];
    int blk = blockIdx.x;
    int kyi = blk&15; int d=(blk>>4)%20; int r2=blk/320; int b=r2&1; int gi=r2>>1;
    int gl4[4]={gA,gB,gC,gD};
    int g=gl4[gi]; int ch=g*20+d;
    int tid=threadIdx.x;
    const float4* src = (const float4*)(ybuf + (((size_t)((g*2+b)*20+d)*16+kyi)*1024));
    #pragma unroll
    for(int u=0;u<2;u++){
        int e=tid+u*128; float4 v=src[e];
        int kzri = e>>4; int xx=(e&15)*4;
        *(float4*)(ylx + kzri*68 + xx) = v;
    }
    for(int tt=tid;tt<1024;tt+=128){
        int ki=tt>>6, y=tt&63;
        cxl[ki*65+y]=tab[3584+tt]; sxl[ki*65+y]=tab[4608+tt];
    }
    float s1=0,s2=0;
    if(tid<64){
        size_t pi=((size_t)(b*80+ch)*64+tid)*2;
        s1=partZY[pi]; s2=partZY[pi+1];
    }
    s1=wred(s1); s2=wred(s2);
    if(tid==0){
        float mean=s1*(1.0f/196608.0f);
        float var=s2*(1.0f/196608.0f)-mean*mean;
        scs[0]=rsqrtf(var+EPSV);
    }
    __syncthreads();
    float sc = scs[0];
    int kxi=tid>>3, kz=tid&7;
    const float* yr = ylx + (kz*2)*68;
    const float* yi = ylx + (kz*2+1)*68;
    const float* cx = cxl + kxi*65;
    const float* sx = sxl + kxi*65;
    float fr=0, fi=0;
    #pragma unroll 8
    for(int xx=0;xx<64;xx++){
        float a=yr[xx], e2=yi[xx];
        float c=cx[xx], s=sx[xx];
        fr += a*c + e2*s;
        fi += e2*c - a*s;
    }
    fr*=sc; fi*=sc;
    if(kxi==0 && kyi==0 && kz==0){ fr=0.0f; fi=0.0f; }
    size_t idx = ((size_t)(b*80+ch)*2048 + (size_t)((kxi*16+kyi)*8+kz))*2;
    fbufC[idx]=fr; fbufC[idx+1]=fi;
}

// ---------------- spectral multiply, PAIR-MERGED (it = blk/320) ----------------
__global__ void __launch_bounds__(256) k_spec2(const float* __restrict__ fbufC,
        const float* __restrict__ sw, float* __restrict__ gbuf,
        float* __restrict__ stat2, int li0,
        int i0, int gA1, int gA2, int i1, int gB1, int gB2){
    __shared__ float part[2112];
    int blk = blockIdx.x;
    int it = blk/320; int r = blk - it*320;
    int m1p = r & 3, o = (r>>2)%20, q = r/80;
    int li = li0 + it;
    int g0 = it ? i1 : i0;
    int g1 = it ? gB1 : gA1;
    int g2 = it ? gB2 : gA2;
    int tid = threadIdx.x;
    int t64 = tid & 63, cc = tid >> 6;
    if(q==0 && m1p==0 && tid<2){
        stat2[((it*2+tid)*20+o)*2]=0.f; stat2[((it*2+tid)*20+o)*2+1]=0.f;
    }
    int offx = (q&1)*8, offy = (q>>1)*8;
    int m1 = m1p*2 + (t64>>5);
    int m2 = (t64>>2)&7;
    int m3 = (t64&3)*2;
    int tw = m1*64 + m2*8 + m3;
    int kxi = m1+offx, kyi = m2+offy;
    int fo = (kxi*16 + kyi)*8 + m3;   // even
    const float4* wp = (const float4*)(sw + (((size_t)(li*4+q)*1600) + o)*1024 + (size_t)tw*2);
    const float4* fb = (const float4*)fbufC + (fo>>1);
    float r00=0,i00=0,r01=0,i01=0, r10=0,i10=0,r11=0,i11=0;
    int c0 = cc*5;
    #pragma unroll
    for(int u=0;u<5;u++){
        int c = c0+u;
        float4 wa = wp[(size_t)c*5120];
        float4 wb4= wp[(size_t)(c+20)*5120];
        float wr0 = wa.x + wb4.x, wi0 = wa.y + wb4.y, wr1 = wa.z + wb4.z, wi1 = wa.w + wb4.w;
        float4 f0 = fb[(size_t)(g0*20+c)*1024];
        float4 f1 = fb[(size_t)(80+g0*20+c)*1024];
        r00 += f0.x*wr0 - f0.y*wi0; i00 += f0.x*wi0 + f0.y*wr0;
        r01 += f0.z*wr1 - f0.w*wi1; i01 += f0.z*wi1 + f0.w*wr1;
        r10 += f1.x*wr0 - f1.y*wi0; i10 += f1.x*wi0 + f1.y*wr0;
        r11 += f1.z*wr1 - f1.w*wi1; i11 += f1.z*wi1 + f1.w*wr1;
    }
    #pragma unroll
    for(int u=0;u<5;u++){
        int c = c0+u;
        float4 wa = wp[(size_t)(c+40)*5120];
        float4 f0 = fb[(size_t)(g1*20+c)*1024];
        float4 f1 = fb[(size_t)(80+g1*20+c)*1024];
        r00 += f0.x*wa.x - f0.y*wa.y; i00 += f0.x*wa.y + f0.y*wa.x;
        r01 += f0.z*wa.z - f0.w*wa.w; i01 += f0.z*wa.w + f0.w*wa.z;
        r10 += f1.x*wa.x - f1.y*wa.y; i10 += f1.x*wa.y + f1.y*wa.x;
        r11 += f1.z*wa.z - f1.w*wa.w; i11 += f1.z*wa.w + f1.w*wa.z;
    }
    #pragma unroll
    for(int u=0;u<5;u++){
        int c = c0+u;
        float4 wa = wp[(size_t)(c+60)*5120];
        float4 f0 = fb[(size_t)(g2*20+c)*1024];
        float4 f1 = fb[(size_t)(80+g2*20+c)*1024];
        r00 += f0.x*wa.x - f0.y*wa.y; i00 += f0.x*wa.y + f0.y*wa.x;
        r01 += f0.z*wa.z - f0.w*wa.w; i01 += f0.z*wa.w + f0.w*wa.z;
        r10 += f1.x*wa.x - f1.y*wa.y; i10 += f1.x*wa.y + f1.y*wa.x;
        r11 += f1.z*wa.z - f1.w*wa.w; i11 += f1.z*wa.w + f1.w*wa.z;
    }
    float vals[8]={r00,i00,r01,i01,r10,i10,r11,i11};
    #pragma unroll
    for(int e=0;e<8;e++) part[t64*33 + e*4 + cc] = vals[e];
    __syncthreads();
    if(cc==0){
        float acc[8];
        #pragma unroll
        for(int e=0;e<8;e++){
            const float* p = part + t64*33 + e*4;
            acc[e] = p[0]+p[1]+p[2]+p[3];
        }
        float* gb = gbuf + (size_t)it*163840;
        float4* gg0 = (float4*)(gb + (size_t)o*4096 + fo*2);
        float4* gg1 = (float4*)(gb + (size_t)(20+o)*4096 + fo*2);
        *gg0 = make_float4(acc[0],acc[1],acc[2],acc[3]);
        *gg1 = make_float4(acc[4],acc[5],acc[6],acc[7]);
    }
}

// ---------------- fused inverse x + y + Parseval stats, PAIR-MERGED ----------------
__global__ void k_inv2(const float* __restrict__ gbuf, float* __restrict__ iybuf,
                       float* __restrict__ stat2, const float* __restrict__ tab){
    __shared__ __align__(16) float gl[4096];
    __shared__ float tmp[256];
    __shared__ float cl[1088], sl[1088];   // [y][ki] stride 17
    __shared__ float ig[4];
    int blk = blockIdx.x;
    int it = blk/2560; int r = blk - it*2560;
    int nx = r&63, o = (r>>6)%20, b = r/1280;
    const float4* src4 = (const float4*)(gbuf + (size_t)it*163840 + (size_t)(b*20+o)*4096);
    for(int t=threadIdx.x;t<1024;t+=blockDim.x) ((float4*)gl)[t]=src4[t];
    for(int t=threadIdx.x;t<1024;t+=blockDim.x){
        int y=t>>4, ki=t&15;
        cl[y*17+ki]=tab[1536+t]; sl[y*17+ki]=tab[2560+t];
    }
    __syncthreads();
    {
        int kyi = threadIdx.x>>3, kz = threadIdx.x&7;
        float ar=0, ai=0;
        #pragma unroll 4
        for(int kxi=0;kxi<16;kxi++){
            float gr = gl[((kxi*16+kyi)*8+kz)*2], gi2 = gl[((kxi*16+kyi)*8+kz)*2+1];
            float c = cl[nx*17+kxi], s = sl[nx*17+kxi];
            ar += gr*c - gi2*s;
            ai += gi2*c + gr*s;
        }
        tmp[threadIdx.x*2]   = ar*(1.0f/64.0f);
        tmp[threadIdx.x*2+1] = ai*(1.0f/64.0f);
    }
    __syncthreads();
    float p1=0,p2=0;
    for(int j=0;j<4;j++){
        int out = threadIdx.x + j*128;
        int ny = out>>3, kz = out&7;
        float ar=0, ai=0;
        #pragma unroll 4
        for(int kyi=0;kyi<16;kyi++){
            float vr = tmp[(kyi*8+kz)*2], vi = tmp[(kyi*8+kz)*2+1];
            float c = cl[ny*17+kyi], s = sl[ny*17+kyi];
            ar += vr*c - vi*s;
            ai += vi*c + vr*s;
        }
        ar *= (1.0f/64.0f); ai *= (1.0f/64.0f);
        size_t idx = ((((size_t)((it*2+b)*20+o)*64+nx)*64+ny)*8+kz)*2;
        iybuf[idx]=ar; iybuf[idx+1]=ai;
        if(kz==0){ p1 += ar; p2 += ar*ar; }
        else p2 += 2.0f*(ar*ar+ai*ai);
    }
    p2 *= (1.0f/48.0f);
    float r1=wred(p1), r2=wred(p2);
    int wv = threadIdx.x>>6;
    if((threadIdx.x&63)==0){ ig[wv*2]=r1; ig[wv*2+1]=r2; }
    __syncthreads();
    if(threadIdx.x==0){
        atomicAdd(&stat2[((it*2+b)*20+o)*2],   ig[0]+ig[2]);
        atomicAdd(&stat2[((it*2+b)*20+o)*2+1], ig[1]+ig[3]);
    }
}

// ---------------- pass D PAIR-MERGED, SEQUENTIAL halves (low reg pressure) ----------------
// iter A: z-inv+norm+MLP+residual -> write group i0 (iter B never reads i0).
// iter B: same for group i1. All residual reads are at the thread's own columns.
__global__ void __launch_bounds__(256) k_passD2(
        const float* __restrict__ iybuf,
        const float* __restrict__ w1, const float* __restrict__ b1,
        const float* __restrict__ w2, const float* __restrict__ b2,
        const float* __restrict__ ww, const float* __restrict__ wb,
        float* __restrict__ h,
        const float* __restrict__ stat2, const float* __restrict__ tab,
        int li0, int i0, int i1, int gA1, int gA2, int gB1, int gB2,
        int fA0,int fA1,int fA2, int fB0,int fB1,int fB2){
    __shared__ __align__(16) float dl[5120];
    __shared__ float m2l[2][20], s2l[2][20];
    __shared__ float czl[384], szl[384];
    int blk = blockIdx.x;
    int nyt = blk&7, nx=(blk>>3)&63, b = blk>>9;
    int tid = threadIdx.x;
    for(int u=tid; u<1280; u+=256){
        int itu = (u>=640)?1:0; int rem = u - itu*640;
        int o = rem>>5, j = rem&31;
        const float4* s4 = (const float4*)(iybuf +
            ((((size_t)((itu*2+b)*20+o)*64+nx)*64 + nyt*8)*16));
        ((float4*)dl)[itu*640 + o*32 + j] = s4[j];
    }
    if(tid<40){
        int itq = tid/20, oq = tid - itq*20;
        float S1 = stat2[((itq*2+b)*20+oq)*2], S2 = stat2[((itq*2+b)*20+oq)*2+1];
        float mean = S1*(1.0f/196608.0f);
        float var = S2*(1.0f/196608.0f) - mean*mean;
        m2l[itq][oq]=mean; s2l[itq][oq]=rsqrtf(var+EPSV);
    }
    for(int t=tid;t<384;t+=256){ czl[t]=tab[768+t]; szl[t]=tab[1152+t]; }
    __syncthreads();
    if(tid>=192) return;
    int p0 = tid*2;
    int nyl = p0/48, nz0 = p0 - nyl*48;
    int sb = (nx*64 + nyt*8)*48;
    const float* hb = h + (size_t)(b*80)*SPAT + sb + p0;
    // ================= iteration A =================
    {
        float vj0[20], vj1[20];
        #pragma unroll
        for(int o=0;o<20;o++){
            const float* dd = dl + o*128 + nyl*16;
            float a0 = dd[0], a1 = dd[0];
            #pragma unroll
            for(int k=1;k<8;k++){
                float dr = dd[k*2], di = dd[k*2+1];
                a0 += 2.0f*(dr*czl[k*48+nz0]   - di*szl[k*48+nz0]);
                a1 += 2.0f*(dr*czl[k*48+nz0+1] - di*szl[k*48+nz0+1]);
            }
            vj0[o] = (a0*(1.0f/48.0f) - m2l[0][o])*s2l[0][o];
            vj1[o] = (a1*(1.0f/48.0f) - m2l[0][o])*s2l[0][o];
        }
        const float* W1 = w1 + li0*400; const float* W2 = w2 + li0*400;
        const float* B1 = b1 + li0*20;  const float* B2 = b2 + li0*20;
        float t10[20], t11[20];
        #pragma unroll
        for(int oo=0;oo<20;oo++){
            float a0=B1[oo], a1=a0;
            #pragma unroll
            for(int j=0;j<20;j++){ float w=W1[oo*20+j]; a0+=vj0[j]*w; a1+=vj1[j]*w; }
            t10[oo]=geluf(a0); t11[oo]=geluf(a1);
        }
        float o0[20], o1[20];
        #pragma unroll
        for(int oo=0;oo<20;oo++){
            float bb = B2[oo] + wb[li0*20+oo];
            float a0=bb, a1=bb;
            #pragma unroll
            for(int j=0;j<20;j++){ float w=W2[oo*20+j]; a0+=t10[j]*w; a1+=t11[j]*w; }
            o0[oo]=a0; o1[oo]=a1;
        }
        const float* W = ww + li0*1600;
        for(int c=0;c<20;c++){
            float2 vv = *(const float2*)(hb + (size_t)(i0*20+c)*SPAT);
            if(fA0){ vv.x=geluf(vv.x); vv.y=geluf(vv.y); }
            #pragma unroll
            for(int o=0;o<20;o++){
                float w = W[o*80+c] + W[o*80+20+c];
                o0[o]+=w*vv.x; o1[o]+=w*vv.y;
            }
        }
        for(int c=0;c<20;c++){
            float2 vv = *(const float2*)(hb + (size_t)(gA1*20+c)*SPAT);
            if(fA1){ vv.x=geluf(vv.x); vv.y=geluf(vv.y); }
            #pragma unroll
            for(int o=0;o<20;o++){
                float w = W[o*80+40+c];
                o0[o]+=w*vv.x; o1[o]+=w*vv.y;
            }
        }
        for(int c=0;c<20;c++){
            float2 vv = *(const float2*)(hb + (size_t)(gA2*20+c)*SPAT);
            if(fA2){ vv.x=geluf(vv.x); vv.y=geluf(vv.y); }
            #pragma unroll
            for(int o=0;o<20;o++){
                float w = W[o*80+60+c];
                o0[o]+=w*vv.x; o1[o]+=w*vv.y;
            }
        }
        #pragma unroll
        for(int o=0;o<20;o++)
            *(float2*)(h + (size_t)(b*80+i0*20+o)*SPAT + sb + p0) = make_float2(o0[o],o1[o]);
    }
    // ================= iteration B ================= (gather set excludes i0)
    {
        int li1 = li0+1;
        float vj0[20], vj1[20];
        #pragma unroll
        for(int o=0;o<20;o++){
            const float* dd = dl + 2560 + o*128 + nyl*16;
            float a0 = dd[0], a1 = dd[0];
            #pragma unroll
            for(int k=1;k<8;k++){
                float dr = dd[k*2], di = dd[k*2+1];
                a0 += 2.0f*(dr*czl[k*48+nz0]   - di*szl[k*48+nz0]);
                a1 += 2.0f*(dr*czl[k*48+nz0+1] - di*szl[k*48+nz0+1]);
            }
            vj0[o] = (a0*(1.0f/48.0f) - m2l[1][o])*s2l[1][o];
            vj1[o] = (a1*(1.0f/48.0f) - m2l[1][o])*s2l[1][o];
        }
        const float* W1 = w1 + li1*400; const float* W2 = w2 + li1*400;
        const float* B1 = b1 + li1*20;  const float* B2 = b2 + li1*20;
        float t10[20], t11[20];
        #pragma unroll
        for(int oo=0;oo<20;oo++){
            float a0=B1[oo], a1=a0;
            #pragma unroll
            for(int j=0;j<20;j++){ float w=W1[oo*20+j]; a0+=vj0[j]*w; a1+=vj1[j]*w; }
            t10[oo]=geluf(a0); t11[oo]=geluf(a1);
        }
        float o0[20], o1[20];
        #pragma unroll
        for(int oo=0;oo<20;oo++){
            float bb = B2[oo] + wb[li1*20+oo];
            float a0=bb, a1=bb;
            #pragma unroll
            for(int j=0;j<20;j++){ float w=W2[oo*20+j]; a0+=t10[j]*w; a1+=t11[j]*w; }
            o0[oo]=a0; o1[oo]=a1;
        }
        const float* W = ww + li1*1600;
        for(int c=0;c<20;c++){
            float2 vv = *(const float2*)(hb + (size_t)(i1*20+c)*SPAT);
            if(fB0){ vv.x=geluf(vv.x); vv.y=geluf(vv.y); }
            #pragma unroll
            for(int o=0;o<20;o++){
                float w = W[o*80+c] + W[o*80+20+c];
                o0[o]+=w*vv.x; o1[o]+=w*vv.y;
            }
        }
        for(int c=0;c<20;c++){
            float2 vv = *(const float2*)(hb + (size_t)(gB1*20+c)*SPAT);
            if(fB1){ vv.x=geluf(vv.x); vv.y=geluf(vv.y); }
            #pragma unroll
            for(int o=0;o<20;o++){
                float w = W[o*80+40+c];
                o0[o]+=w*vv.x; o1[o]+=w*vv.y;
            }
        }
        for(int c=0;c<20;c++){
            float2 vv = *(const float2*)(hb + (size_t)(gB2*20+c)*SPAT);
            if(fB2){ vv.x=geluf(vv.x); vv.y=geluf(vv.y); }
            #pragma unroll
            for(int o=0;o<20;o++){
                float w = W[o*80+60+c];
                o0[o]+=w*vv.x; o1[o]+=w*vv.y;
            }
        }
        #pragma unroll
        for(int o=0;o<20;o++)
            *(float2*)(h + (size_t)(b*80+i1*20+o)*SPAT + sb + p0) = make_float2(o0[o],o1[o]);
    }
}

// ---------------- output head: 2 columns/thread, SGPR weights ----------------
__global__ void __launch_bounds__(256) k_head(const float* __restrict__ h,
        const float* __restrict__ qw1, const float* __restrict__ qb1,
        const float* __restrict__ qw2, const float* __restrict__ qb2,
        float* __restrict__ out){
    int g = blockIdx.x & 3;
    int t = (blockIdx.x>>2)*256 + threadIdx.x;   // 0..196607 column-pairs
    if(t >= 196608) return;
    int b = (t>=98304) ? 1 : 0; int col = (t - b*98304)*2;
    const float* hb = h + (size_t)(b*80+g*20)*SPAT + col;
    float2 in20[20];
    #pragma unroll
    for(int j=0;j<20;j++) in20[j] = *(const float2*)(hb + (size_t)j*SPAT);
    float2 o20[20];
    #pragma unroll
    for(int o2=0;o2<20;o2++){ float bv = qb2[g*20+o2]; o20[o2].x=bv; o20[o2].y=bv; }
    for(int o8=0;o8<80;o8++){
        float bv = qb1[g*80+o8];
        float a0 = bv, a1 = bv;
        #pragma unroll
        for(int j=0;j<20;j++){
            float w = qw1[g*1600 + o8*20 + j];
            a0 += in20[j].x*w; a1 += in20[j].y*w;
        }
        a0 = geluf(a0); a1 = geluf(a1);
        #pragma unroll
        for(int o2=0;o2<20;o2++){
            float w = qw2[g*1600 + o2*80 + o8];
            o20[o2].x += a0*w; o20[o2].y += a1*w;
        }
    }
    float* op0 = out + ((size_t)(b*SPAT)+col)*80 + g*20;
    float* op1 = op0 + 80;
    #pragma unroll
    for(int q2=0;q2<5;q2++){
        *(float4*)(op0 + q2*4) = make_float4(o20[q2*4].x,o20[q2*4+1].x,o20[q2*4+2].x,o20[q2*4+3].x);
        *(float4*)(op1 + q2*4) = make_float4(o20[q2*4].y,o20[q2*4+1].y,o20[q2*4+2].y,o20[q2*4+3].y);
    }
}

extern "C" void kernel_launch(void* const* d_in, const int* in_sizes, int n_in,
                              void* d_out, int out_size, void* d_ws, size_t ws_size,
                              hipStream_t stream){
    (void)in_sizes; (void)n_in; (void)out_size;
    const float* x    = (const float*)d_in[0];
    const float* p_w  = (const float*)d_in[1];
    const float* p_b  = (const float*)d_in[2];
    const float* spec = (const float*)d_in[3];
    const float* w1   = (const float*)d_in[4];
    const float* b1   = (const float*)d_in[5];
    const float* w2   = (const float*)d_in[6];
    const float* b2   = (const float*)d_in[7];
    const float* ww   = (const float*)d_in[8];
    const float* wb   = (const float*)d_in[9];
    const float* qw1  = (const float*)d_in[10];
    const float* qb1  = (const float*)d_in[11];
    const float* qw2  = (const float*)d_in[12];
    const float* qb2  = (const float*)d_in[13];
    float* out = (float*)d_out;
    float* ws  = (float*)d_ws;

    if(ws_size < (size_t)40330912*4) return;  // ~161 MB scratch

    float* h      = ws;                       // 31,457,280
    float* ybuf   = ws + 31457280;            //  2,621,440
    float* gbuf   = ws + 34078720;            //    327,680 (2 iters)
    float* iyb    = ws + 34406400;            //  5,242,880 (2 iters)
    float* fbufC  = ws + 39649280;            //    655,360
    float* partZY = ws + 40304640;            //     20,480
    float* stat2  = ws + 40325120;            //        160 (2 iters)
    float* tab    = ws + 40325280;            //      5,632

    k_tables<<<1,256,0,stream>>>(tab);
    k_lift<<<1536,256,0,stream>>>(x, p_w, p_b, h);

    static const int ORD3[4][3] = {{0,1,2},{1,2,3},{2,3,0},{3,0,1}};
    for(int l=0;l<4;l++){
        int lf = (l>0)?1:0;
        for(int bi=0;bi<2;bi++){
            if(bi==0){
                // all 4 groups from pre-layer h (iters 0,1 read only pre-layer channels)
                k_zy  <<<10240,256,0,stream>>>(h, ybuf, partZY, tab, 0,1,2,3, lf);
                k_xdft<<< 2560,128,0,stream>>>(ybuf, fbufC, partZY, tab, 0,1,2,3);
            } else {
                // groups 0,1 freshly updated this layer -> no gelu
                k_zy  <<< 5120,256,0,stream>>>(h, ybuf, partZY, tab, 0,1,0,0, 0);
                k_xdft<<< 1280,128,0,stream>>>(ybuf, fbufC, partZY, tab, 0,1,0,0);
            }
            int i0 = bi*2, i1 = i0+1, li0 = l*4+i0;
            int gA1=ORD3[i0][1], gA2=ORD3[i0][2];
            int gB1=ORD3[i1][1], gB2=ORD3[i1][2];
            k_spec2<<< 640,256,0,stream>>>(fbufC, spec, gbuf, stat2, li0,
                                           i0,gA1,gA2, i1,gB1,gB2);
            k_inv2 <<<5120,128,0,stream>>>(gbuf, iyb, stat2, tab);
            int fA0 = lf;
            int fA1 = (gA1<i0)?0:lf;
            int fA2 = (gA2<i0)?0:lf;
            int fB0 = lf;
            int fB1 = (gB1<i1)?0:lf;
            int fB2 = (gB2<i1)?0:lf;
            k_passD2<<<1024,256,0,stream>>>(iyb, w1,b1,w2,b2, ww,wb, h, stat2, tab,
                                            li0, i0,i1, gA1,gA2, gB1,gB2,
                                            fA0,fA1,fA2, fB0,fB1,fB2);
        }
    }
    k_head<<<3072,256,0,stream>>>(h, qw1, qb1, qw2, qb2, out);
}